// Round 7
// baseline (548.863 us; speedup 1.0000x reference)
//
#include <hip/hip_runtime.h>
#include <stdint.h>

#define HW 262144            // 512*512
#define ACQ_N 2097152        // 8*1*512*512

// hw-native transcendentals (1 instr each)
#define LOG2F(x) __builtin_amdgcn_logf(x)
#define EXP2F(x) __builtin_amdgcn_exp2f(x)
#define SQRTF(x) __builtin_amdgcn_sqrtf(x)
#define RCPF(x)  __builtin_amdgcn_rcpf(x)

#define ROTL(x, r) __builtin_amdgcn_alignbit((x), (x), (32 - (r)) & 31)

// ---------- host-side threefry2x32 for key derivation ----------
static inline void tf2x32_host(uint32_t k0, uint32_t k1, uint32_t c0, uint32_t c1,
                               uint32_t& o0, uint32_t& o1) {
  const uint32_t ks2 = k0 ^ k1 ^ 0x1BD11BDAu;
  uint32_t x0 = c0 + k0, x1 = c1 + k1;
#define TFR(r) { x0 += x1; x1 = (x1 << (r)) | (x1 >> (32 - (r))); x1 ^= x0; }
  TFR(13) TFR(15) TFR(26) TFR(6)
  x0 += k1;  x1 += ks2 + 1u;
  TFR(17) TFR(29) TFR(16) TFR(24)
  x0 += ks2; x1 += k0 + 2u;
  TFR(13) TFR(15) TFR(26) TFR(6)
  x0 += k0;  x1 += k1 + 3u;
  TFR(17) TFR(29) TFR(16) TFR(24)
  x0 += k1;  x1 += ks2 + 4u;
  TFR(13) TFR(15) TFR(26) TFR(6)
  x0 += ks2; x1 += k0 + 5u;
#undef TFR
  o0 = x0; o1 = x1;
}

// device: partitionable random_bits(32) for counter (0, idx): o0^o1
__device__ __forceinline__ uint32_t rbits32(uint32_t k0, uint32_t k1, uint32_t idx) {
  const uint32_t ks2 = k0 ^ k1 ^ 0x1BD11BDAu;
  uint32_t x0 = k0, x1 = idx + k1;
#define TFR(r) { x0 += x1; x1 = ROTL(x1, r); x1 ^= x0; }
  TFR(13) TFR(15) TFR(26) TFR(6)
  x0 += k1;  x1 += ks2 + 1u;
  TFR(17) TFR(29) TFR(16) TFR(24)
  x0 += ks2; x1 += k0 + 2u;
  TFR(13) TFR(15) TFR(26) TFR(6)
  x0 += k0;  x1 += k1 + 3u;
  TFR(17) TFR(29) TFR(16) TFR(24)
  x0 += k1;  x1 += ks2 + 4u;
  TFR(13) TFR(15) TFR(26) TFR(6)
  x0 += ks2; x1 += k0 + 5u;
#undef TFR
  return x0 ^ x1;
}

__device__ __forceinline__ float unit_from_bits(uint32_t b) {
  return __uint_as_float((b >> 9) | 0x3F800000u) - 1.0f;
}

// z = sqrt(2)*erfinv(x), Giles poly pre-scaled by sqrt(2); far branch real-branched.
__device__ __forceinline__ float sqrt2_erfinv(float x) {
  float ome = fmaf(-x, x, 1.0f);
  float w = -0.69314718056f * LOG2F(ome);
  float wn = w - 2.5f;
  float p = 3.974065e-08f;
  p = fmaf(p, wn, 4.854641e-07f);
  p = fmaf(p, wn, -4.982823e-06f);
  p = fmaf(p, wn, -6.210531e-06f);
  p = fmaf(p, wn, 3.091200e-04f);
  p = fmaf(p, wn, -1.773035e-03f);
  p = fmaf(p, wn, -5.908135e-03f);
  p = fmaf(p, wn, 3.488029e-01f);
  p = fmaf(p, wn, 2.123314e+00f);
  if (__builtin_expect(w >= 5.0f, 0)) {
    float wf = SQRTF(w) - 3.0f;
    float q = -2.831458e-04f;
    q = fmaf(q, wf, 1.427657e-04f);
    q = fmaf(q, wf, 1.908260e-03f);
    q = fmaf(q, wf, -5.195013e-03f);
    q = fmaf(q, wf, 8.116892e-03f);
    q = fmaf(q, wf, -1.0779791e-02f);
    q = fmaf(q, wf, 1.3348579e-02f);
    q = fmaf(q, wf, 1.416582e+00f);
    q = fmaf(q, wf, 4.006434e+00f);
    p = q;
  }
  return p * x;
}

// ================= compacted path =================
// ws layout: u32 ctr[8][4] @0 ; u32 ctr2[8][4] @128 ; u32 classbase[8][4] @256 ;
//            float biasacc[8] @384 ; u32 slotidx[8][HW] @512

// phase 1: per-(batch,class) totals + channel-1 bias sum
__global__ __launch_bounds__(256) void count_cls(const float* __restrict__ inp,
                                                 uint32_t* __restrict__ ctr,
                                                 float* __restrict__ biasacc) {
  int blk = blockIdx.x;                 // 512 blocks: 8 batches x 64 chunks
  int b = blk >> 6, chunk = blk & 63;
  const float* pb = inp + (size_t)b * 5 * HW;
  int off = chunk * 4096 + threadIdx.x;
  int lane = threadIdx.x & 63, wid = threadIdx.x >> 6;

  int lc0 = 0, lc1 = 0, lc2 = 0, lc3 = 0;
  float s = 0.0f;
#pragma unroll
  for (int k = 0; k < 16; ++k) {
    int i = off + k * 256;
    float f2 = pb[2 * HW + i];
    float f4 = pb[4 * HW + i];
    s += pb[HW + i];
    int cls = (f2 > 0.0f ? 1 : 0) | (f4 > 0.0f ? 2 : 0);
    lc0 += (cls == 0); lc1 += (cls == 1); lc2 += (cls == 2); lc3 += (cls == 3);
  }
  for (int o = 32; o; o >>= 1) {
    lc0 += __shfl_down(lc0, o); lc1 += __shfl_down(lc1, o);
    lc2 += __shfl_down(lc2, o); lc3 += __shfl_down(lc3, o);
    s   += __shfl_down(s, o);
  }
  __shared__ uint32_t scnt[4][4];
  __shared__ float sb[4];
  if (lane == 0) {
    scnt[wid][0] = lc0; scnt[wid][1] = lc1;
    scnt[wid][2] = lc2; scnt[wid][3] = lc3;
    sb[wid] = s;
  }
  __syncthreads();
  if (threadIdx.x == 0) {
#pragma unroll
    for (int c = 0; c < 4; ++c)
      atomicAdd(&ctr[b * 4 + c],
                scnt[0][c] + scnt[1][c] + scnt[2][c] + scnt[3][c]);
    atomicAdd(&biasacc[b], sb[0] + sb[1] + sb[2] + sb[3]);
  }
}

// phase 2: exclusive scan over classes per batch
__global__ __launch_bounds__(64) void scan_cls(const uint32_t* __restrict__ ctr,
                                               uint32_t* __restrict__ classbase) {
  int b = threadIdx.x;
  if (b < 8) {
    uint32_t t0 = ctr[b * 4 + 0], t1 = ctr[b * 4 + 1], t2 = ctr[b * 4 + 2];
    classbase[b * 4 + 0] = 0;
    classbase[b * 4 + 1] = t0;
    classbase[b * 4 + 2] = t0 + t1;
    classbase[b * 4 + 3] = t0 + t1 + t2;
  }
}

// phase 3: scatter pixel indices, per-batch sorted by class
__global__ __launch_bounds__(256) void scatter_cls(const float* __restrict__ inp,
                                                   const uint32_t* __restrict__ classbase,
                                                   uint32_t* __restrict__ ctr2,
                                                   uint32_t* __restrict__ slotidx) {
  int b = blockIdx.x >> 10;
  int rem = ((blockIdx.x & 1023) << 8) | threadIdx.x;
  int tid = threadIdx.x, wid = tid >> 6, lane = tid & 63;
  const float* pb = inp + (size_t)b * 5 * HW;

  float f2 = pb[2 * HW + rem];
  float f4 = pb[4 * HW + rem];
  int cls = (f2 > 0.0f ? 1 : 0) | (f4 > 0.0f ? 2 : 0);

  uint64_t ball[4];
#pragma unroll
  for (int c = 0; c < 4; ++c) ball[c] = __ballot(cls == c);
  uint64_t below = (1ull << lane) - 1ull;
  int rank = __popcll(ball[cls] & below);

  __shared__ uint32_t wcnt[4][4], wbase[4][4], gbase[4];
  if (lane == 0) {
#pragma unroll
    for (int c = 0; c < 4; ++c) wcnt[wid][c] = (uint32_t)__popcll(ball[c]);
  }
  __syncthreads();
  if (tid == 0) {
#pragma unroll
    for (int c = 0; c < 4; ++c) {
      uint32_t run = 0;
#pragma unroll
      for (int w = 0; w < 4; ++w) { wbase[w][c] = run; run += wcnt[w][c]; }
      gbase[c] = classbase[b * 4 + c] + atomicAdd(&ctr2[b * 4 + c], run);
    }
  }
  __syncthreads();
  uint32_t slot = gbase[cls] + wbase[wid][cls] + (uint32_t)rank;
  slotidx[(size_t)b * HW + slot] = (uint32_t)rem;
}

// phase 4: one thread per slot; waves are class-pure -> skip unneeded ciphers
__global__ __launch_bounds__(256) void acquire_cls(
    const float* __restrict__ inp, const int* __restrict__ frames,
    const float* __restrict__ biasacc, const uint32_t* __restrict__ slotidx,
    float* __restrict__ out,
    uint32_t ku0, uint32_t ku1, uint32_t kn0, uint32_t kn1) {
  int b = blockIdx.x >> 10;
  int slot = ((blockIdx.x & 1023) << 8) | threadIdx.x;
  uint32_t rem = slotidx[(size_t)b * HW + slot];

  __shared__ float s_bias;
  if (threadIdx.x == 0)
    s_bias = fmaxf(biasacc[b] * (1.0f / 262144.0f), 0.0f);

  const float* pb = inp + (size_t)b * 5 * HW;
  float img = pb[rem];
  float fw  = fmaxf(pb[2 * HW + rem], 0.0f);
  float fa  = fmaxf(pb[3 * HW + rem], 0.0f);
  float gw  = fmaxf(pb[4 * HW + rem], 0.0f);
  __syncthreads();
  float base = img + s_bias;

  int nf = frames[b];                      // block-uniform
  bool fAny = __any(fw > 0.0f);            // wave-uniform
  bool gAny = __any(gw > 0.0f);
  float nfa = -fa;
  float fac = fa * 0.52876637294f;         // fa*log2(ln2)

  float res;
  if (fAny || gAny) {
    uint32_t idx = (uint32_t)(b * 16) * (uint32_t)HW + rem;
    float acc = 0.0f;
    for (int f = 0; f < nf; ++f) {
      float term = base;
      if (fAny) {
        uint32_t ub = rbits32(ku0, ku1, idx);
        float u = unit_from_bits(ub);
        u = fminf(fmaxf(u, 1e-6f), 0.999999f);
        float pw = EXP2F(fmaf(nfa, LOG2F(-LOG2F(u)), fac));
        term = fmaf(fw, pw, term);
      }
      if (gAny) {
        uint32_t nb = rbits32(kn0, kn1, idx);
        float z = sqrt2_erfinv(fmaf(unit_from_bits(nb), 2.0f, -0.99999994f));
        term = fmaf(gw, z, term);
      }
      idx += (uint32_t)HW;
      acc += fminf(fmaxf(term, 0.0f), 1.0f);
    }
    res = acc * RCPF((float)nf);
  } else {
    res = fminf(fmaxf(base, 0.0f), 1.0f);  // all frames identical
  }
  out[(size_t)b * HW + rem] = res;

  float cpw = EXP2F(nfa * LOG2F(fa + 1.0f));
  out[ACQ_N + (size_t)b * HW + rem] = fminf(fmaxf(fmaf(fw, cpw, base), 0.0f), 1.0f);
}

// ================= fallback path (R5, proven) =================
__global__ __launch_bounds__(256) void bias_partial(const float* __restrict__ inp,
                                                    float* __restrict__ partial) {
  int blk = blockIdx.x;
  int b = blk >> 6, chunk = blk & 63;
  const float4* src = (const float4*)(inp + ((size_t)b * 5 + 1) * HW
                                          + (size_t)chunk * 4096);
  int t = threadIdx.x;
  float s = 0.0f;
#pragma unroll
  for (int k = 0; k < 4; ++k) {
    float4 v = src[t + k * 256];
    s += (v.x + v.y) + (v.z + v.w);
  }
  for (int off = 32; off; off >>= 1) s += __shfl_down(s, off);
  __shared__ float ws4[4];
  if ((t & 63) == 0) ws4[t >> 6] = s;
  __syncthreads();
  if (t == 0) partial[blk] = ws4[0] + ws4[1] + ws4[2] + ws4[3];
}

__global__ __launch_bounds__(256) void acquire_plain(
    const float* __restrict__ inp, const int* __restrict__ frames,
    const float* __restrict__ partial, float* __restrict__ out,
    uint32_t ku0, uint32_t ku1, uint32_t kn0, uint32_t kn1) {
  int b = blockIdx.x >> 10;
  int rem = ((blockIdx.x & 1023) << 8) | threadIdx.x;
  __shared__ float s_bias;
  if (threadIdx.x < 64) {
    float s = partial[(b << 6) | threadIdx.x];
    for (int off = 32; off; off >>= 1) s += __shfl_down(s, off);
    if (threadIdx.x == 0) s_bias = fmaxf(s * (1.0f / 262144.0f), 0.0f);
  }
  const float* pb = inp + (size_t)b * 5 * HW;
  float img = pb[rem];
  float fw  = fmaxf(pb[2 * HW + rem], 0.0f);
  float fa  = fmaxf(pb[3 * HW + rem], 0.0f);
  float gw  = fmaxf(pb[4 * HW + rem], 0.0f);
  __syncthreads();
  float base = img + s_bias;
  int nf = frames[b];
  float nfa = -fa;
  float fac = fa * 0.52876637294f;
  uint32_t idx = (uint32_t)(b * 16) * (uint32_t)HW + (uint32_t)rem;
  float acc = 0.0f;
  for (int f = 0; f < nf; ++f) {
    uint32_t ub = rbits32(ku0, ku1, idx);
    uint32_t nb = rbits32(kn0, kn1, idx);
    idx += (uint32_t)HW;
    float u = unit_from_bits(ub);
    u = fminf(fmaxf(u, 1e-6f), 0.999999f);
    float pw = EXP2F(fmaf(nfa, LOG2F(-LOG2F(u)), fac));
    float z = sqrt2_erfinv(fmaf(unit_from_bits(nb), 2.0f, -0.99999994f));
    float s = fmaf(gw, z, fmaf(fw, pw, base));
    acc += fminf(fmaxf(s, 0.0f), 1.0f);
  }
  out[(size_t)b * HW + rem] = acc * RCPF((float)nf);
  float cpw = EXP2F(nfa * LOG2F(fa + 1.0f));
  out[ACQ_N + (size_t)b * HW + rem] = fminf(fmaxf(fmaf(fw, cpw, base), 0.0f), 1.0f);
}

extern "C" void kernel_launch(void* const* d_in, const int* in_sizes, int n_in,
                              void* d_out, int out_size, void* d_ws, size_t ws_size,
                              hipStream_t stream) {
  const float* inp    = (const float*)d_in[0];
  const int*   frames = (const int*)d_in[1];
  float* out = (float*)d_out;

  // jax_threefry_partitionable=True: split(key(42)) foldlike:
  // ku = cipher((0,42),(0,0)), kn = cipher((0,42),(0,1))
  uint32_t ku0, ku1, kn0, kn1;
  tf2x32_host(0u, 42u, 0u, 0u, ku0, ku1);
  tf2x32_host(0u, 42u, 0u, 1u, kn0, kn1);

  const size_t need = 512 + (size_t)8 * HW * 4;
  if (ws_size >= need) {
    uint32_t* ctr       = (uint32_t*)d_ws;                 // 32 u32
    uint32_t* ctr2      = (uint32_t*)((char*)d_ws + 128);  // 32 u32
    uint32_t* classbase = (uint32_t*)((char*)d_ws + 256);  // 32 u32
    float*    biasacc   = (float*)((char*)d_ws + 384);     // 8 f32
    uint32_t* slotidx   = (uint32_t*)((char*)d_ws + 512);  // 8*HW u32
    hipMemsetAsync(d_ws, 0, 512, stream);
    count_cls<<<dim3(512), dim3(256), 0, stream>>>(inp, ctr, biasacc);
    scan_cls<<<dim3(1), dim3(64), 0, stream>>>(ctr, classbase);
    scatter_cls<<<dim3(8192), dim3(256), 0, stream>>>(inp, classbase, ctr2, slotidx);
    acquire_cls<<<dim3(8192), dim3(256), 0, stream>>>(inp, frames, biasacc,
                                                      slotidx, out,
                                                      ku0, ku1, kn0, kn1);
  } else {
    float* partial = (float*)d_ws;   // 512 floats
    bias_partial<<<dim3(512), dim3(256), 0, stream>>>(inp, partial);
    acquire_plain<<<dim3(8192), dim3(256), 0, stream>>>(inp, frames, partial, out,
                                                        ku0, ku1, kn0, kn1);
  }
}

// Round 8
// 177.911 us; speedup vs baseline: 3.0850x; 3.0850x over previous
//
#include <hip/hip_runtime.h>
#include <stdint.h>

#define HW 262144            // 512*512
#define ACQ_N 2097152        // 8*1*512*512

// hw-native transcendentals (1 instr each)
#define LOG2F(x) __builtin_amdgcn_logf(x)
#define EXP2F(x) __builtin_amdgcn_exp2f(x)
#define SQRTF(x) __builtin_amdgcn_sqrtf(x)
#define RCPF(x)  __builtin_amdgcn_rcpf(x)

#define ROTL(x, r) __builtin_amdgcn_alignbit((x), (x), (32 - (r)) & 31)

// ---------- host-side threefry2x32 for key derivation ----------
static inline void tf2x32_host(uint32_t k0, uint32_t k1, uint32_t c0, uint32_t c1,
                               uint32_t& o0, uint32_t& o1) {
  const uint32_t ks2 = k0 ^ k1 ^ 0x1BD11BDAu;
  uint32_t x0 = c0 + k0, x1 = c1 + k1;
#define TFR(r) { x0 += x1; x1 = (x1 << (r)) | (x1 >> (32 - (r))); x1 ^= x0; }
  TFR(13) TFR(15) TFR(26) TFR(6)
  x0 += k1;  x1 += ks2 + 1u;
  TFR(17) TFR(29) TFR(16) TFR(24)
  x0 += ks2; x1 += k0 + 2u;
  TFR(13) TFR(15) TFR(26) TFR(6)
  x0 += k0;  x1 += k1 + 3u;
  TFR(17) TFR(29) TFR(16) TFR(24)
  x0 += k1;  x1 += ks2 + 4u;
  TFR(13) TFR(15) TFR(26) TFR(6)
  x0 += ks2; x1 += k0 + 5u;
#undef TFR
  o0 = x0; o1 = x1;
}

// device: partitionable random_bits(32) for counter (0, idx): o0^o1
__device__ __forceinline__ uint32_t rbits32(uint32_t k0, uint32_t k1, uint32_t idx) {
  const uint32_t ks2 = k0 ^ k1 ^ 0x1BD11BDAu;
  uint32_t x0 = k0, x1 = idx + k1;
#define TFR(r) { x0 += x1; x1 = ROTL(x1, r); x1 ^= x0; }
  TFR(13) TFR(15) TFR(26) TFR(6)
  x0 += k1;  x1 += ks2 + 1u;
  TFR(17) TFR(29) TFR(16) TFR(24)
  x0 += ks2; x1 += k0 + 2u;
  TFR(13) TFR(15) TFR(26) TFR(6)
  x0 += k0;  x1 += k1 + 3u;
  TFR(17) TFR(29) TFR(16) TFR(24)
  x0 += k1;  x1 += ks2 + 4u;
  TFR(13) TFR(15) TFR(26) TFR(6)
  x0 += ks2; x1 += k0 + 5u;
#undef TFR
  return x0 ^ x1;
}

__device__ __forceinline__ float unit_from_bits(uint32_t b) {
  return __uint_as_float((b >> 9) | 0x3F800000u) - 1.0f;
}

// z = sqrt(2)*erfinv(x), Giles poly pre-scaled by sqrt(2); far branch real-branched.
__device__ __forceinline__ float sqrt2_erfinv(float x) {
  float ome = fmaf(-x, x, 1.0f);
  float w = -0.69314718056f * LOG2F(ome);
  float wn = w - 2.5f;
  float p = 3.974065e-08f;
  p = fmaf(p, wn, 4.854641e-07f);
  p = fmaf(p, wn, -4.982823e-06f);
  p = fmaf(p, wn, -6.210531e-06f);
  p = fmaf(p, wn, 3.091200e-04f);
  p = fmaf(p, wn, -1.773035e-03f);
  p = fmaf(p, wn, -5.908135e-03f);
  p = fmaf(p, wn, 3.488029e-01f);
  p = fmaf(p, wn, 2.123314e+00f);
  if (__builtin_expect(w >= 5.0f, 0)) {
    float wf = SQRTF(w) - 3.0f;
    float q = -2.831458e-04f;
    q = fmaf(q, wf, 1.427657e-04f);
    q = fmaf(q, wf, 1.908260e-03f);
    q = fmaf(q, wf, -5.195013e-03f);
    q = fmaf(q, wf, 8.116892e-03f);
    q = fmaf(q, wf, -1.0779791e-02f);
    q = fmaf(q, wf, 1.3348579e-02f);
    q = fmaf(q, wf, 1.416582e+00f);
    q = fmaf(q, wf, 4.006434e+00f);
    p = q;
  }
  return p * x;
}

// ================= compacted path (atomic-free) =================
// ws layout: float partial[512] @0 (2048 B) ; u32 blockcnt[512][4] @2048 (8192 B) ;
//            u32 slotidx[8][HW] @10240 (8 MB)

// phase 1: per-block class counts + per-block bias partial (no atomics)
__global__ __launch_bounds__(256) void count_cls(const float* __restrict__ inp,
                                                 uint32_t* __restrict__ blockcnt,
                                                 float* __restrict__ partial) {
  int blk = blockIdx.x;                 // 512 blocks: 8 batches x 64 chunks
  int b = blk >> 6, chunk = blk & 63;
  const float* pb = inp + (size_t)b * 5 * HW;
  int off = (chunk << 12) + threadIdx.x;
  int lane = threadIdx.x & 63, wid = threadIdx.x >> 6;

  int lc0 = 0, lc1 = 0, lc2 = 0, lc3 = 0;
  float s = 0.0f;
#pragma unroll
  for (int k = 0; k < 16; ++k) {
    int i = off + (k << 8);
    float f2 = pb[2 * HW + i];
    float f4 = pb[4 * HW + i];
    s += pb[HW + i];
    int cls = (f2 > 0.0f ? 1 : 0) | (f4 > 0.0f ? 2 : 0);
    lc0 += (cls == 0); lc1 += (cls == 1); lc2 += (cls == 2); lc3 += (cls == 3);
  }
  for (int o = 32; o; o >>= 1) {
    lc0 += __shfl_down(lc0, o); lc1 += __shfl_down(lc1, o);
    lc2 += __shfl_down(lc2, o); lc3 += __shfl_down(lc3, o);
    s   += __shfl_down(s, o);
  }
  __shared__ uint32_t scnt[4][4];
  __shared__ float sb[4];
  if (lane == 0) {
    scnt[wid][0] = lc0; scnt[wid][1] = lc1;
    scnt[wid][2] = lc2; scnt[wid][3] = lc3;
    sb[wid] = s;
  }
  __syncthreads();
  if (threadIdx.x < 4)
    blockcnt[blk * 4 + threadIdx.x] = scnt[0][threadIdx.x] + scnt[1][threadIdx.x]
                                    + scnt[2][threadIdx.x] + scnt[3][threadIdx.x];
  if (threadIdx.x == 0)
    partial[blk] = sb[0] + sb[1] + sb[2] + sb[3];
}

// phase 2: inline scan + deterministic scatter (no atomics)
__global__ __launch_bounds__(256) void scatter_cls(const float* __restrict__ inp,
                                                   const uint32_t* __restrict__ blockcnt,
                                                   uint32_t* __restrict__ slotidx) {
  int blk = blockIdx.x;                 // 512 blocks: 8 batches x 64 chunks
  int b = blk >> 6, chunk = blk & 63;
  int tid = threadIdx.x, wid = tid >> 6, lane = tid & 63;
  const float* pb = inp + (size_t)b * 5 * HW;

  // inline scan: wave `wid` handles class `wid`; lane = chunk index
  __shared__ uint32_t s_tot[4], s_pre[4], srun[4];
  {
    uint32_t v = blockcnt[(((b << 6) | lane) << 2) | wid];
    uint32_t m = (lane < chunk) ? v : 0u;
    uint32_t tot = v, pre = m;
    for (int o = 32; o; o >>= 1) {
      tot += __shfl_down(tot, o);
      pre += __shfl_down(pre, o);
    }
    if (lane == 0) { s_tot[wid] = tot; s_pre[wid] = pre; }
  }
  __syncthreads();
  if (tid < 4) {
    uint32_t cb = 0;
    for (int cc = 0; cc < tid; ++cc) cb += s_tot[cc];
    srun[tid] = cb + s_pre[tid];      // this block's starting slot for class tid
  }
  __syncthreads();

  __shared__ uint32_t wcnt[4][4];
  uint32_t* sbase = slotidx + (size_t)b * HW;
  for (int k = 0; k < 16; ++k) {
    int i = (chunk << 12) + (k << 8) + tid;
    float f2 = pb[2 * HW + i];
    float f4 = pb[4 * HW + i];
    int cls = (f2 > 0.0f ? 1 : 0) | (f4 > 0.0f ? 2 : 0);

    uint64_t ball[4];
#pragma unroll
    for (int c = 0; c < 4; ++c) ball[c] = __ballot(cls == c);
    uint64_t below = (1ull << lane) - 1ull;
    int rank = __popcll(ball[cls] & below);
    if (lane == 0) {
#pragma unroll
      for (int c = 0; c < 4; ++c) wcnt[wid][c] = (uint32_t)__popcll(ball[c]);
    }
    __syncthreads();
    uint32_t mybase = srun[cls];
    for (int w = 0; w < wid; ++w) mybase += wcnt[w][cls];
    sbase[mybase + (uint32_t)rank] = (uint32_t)i;
    __syncthreads();
    if (tid < 4)
      srun[tid] += wcnt[0][tid] + wcnt[1][tid] + wcnt[2][tid] + wcnt[3][tid];
    __syncthreads();
  }
}

// phase 3: one thread per slot; waves are class-pure -> skip unneeded ciphers
__global__ __launch_bounds__(256) void acquire_cls(
    const float* __restrict__ inp, const int* __restrict__ frames,
    const float* __restrict__ partial, const uint32_t* __restrict__ slotidx,
    float* __restrict__ out,
    uint32_t ku0, uint32_t ku1, uint32_t kn0, uint32_t kn1) {
  int b = blockIdx.x >> 10;
  int slot = ((blockIdx.x & 1023) << 8) | threadIdx.x;
  uint32_t rem = slotidx[(size_t)b * HW + slot];

  __shared__ float s_bias;
  if (threadIdx.x < 64) {
    float s = partial[(b << 6) | threadIdx.x];
    for (int off = 32; off; off >>= 1) s += __shfl_down(s, off);
    if (threadIdx.x == 0) s_bias = fmaxf(s * (1.0f / 262144.0f), 0.0f);
  }

  const float* pb = inp + (size_t)b * 5 * HW;
  float img = pb[rem];
  float fw  = fmaxf(pb[2 * HW + rem], 0.0f);
  float fa  = fmaxf(pb[3 * HW + rem], 0.0f);
  float gw  = fmaxf(pb[4 * HW + rem], 0.0f);
  __syncthreads();
  float base = img + s_bias;

  int nf = frames[b];                      // block-uniform
  bool fAny = __any(fw > 0.0f);            // wave-uniform
  bool gAny = __any(gw > 0.0f);
  float nfa = -fa;
  float fac = fa * 0.52876637294f;         // fa*log2(ln2)

  float res;
  if (fAny || gAny) {
    uint32_t idx = (uint32_t)(b * 16) * (uint32_t)HW + rem;
    float acc = 0.0f;
    for (int f = 0; f < nf; ++f) {
      float term = base;
      if (fAny) {
        uint32_t ub = rbits32(ku0, ku1, idx);
        float u = unit_from_bits(ub);
        u = fminf(fmaxf(u, 1e-6f), 0.999999f);
        float pw = EXP2F(fmaf(nfa, LOG2F(-LOG2F(u)), fac));
        term = fmaf(fw, pw, term);
      }
      if (gAny) {
        uint32_t nb = rbits32(kn0, kn1, idx);
        float z = sqrt2_erfinv(fmaf(unit_from_bits(nb), 2.0f, -0.99999994f));
        term = fmaf(gw, z, term);
      }
      idx += (uint32_t)HW;
      acc += fminf(fmaxf(term, 0.0f), 1.0f);
    }
    res = acc * RCPF((float)nf);
  } else {
    res = fminf(fmaxf(base, 0.0f), 1.0f);  // all frames identical
  }
  out[(size_t)b * HW + rem] = res;

  float cpw = EXP2F(nfa * LOG2F(fa + 1.0f));
  out[ACQ_N + (size_t)b * HW + rem] = fminf(fmaxf(fmaf(fw, cpw, base), 0.0f), 1.0f);
}

// ================= fallback path (R5, proven) =================
__global__ __launch_bounds__(256) void bias_partial(const float* __restrict__ inp,
                                                    float* __restrict__ partial) {
  int blk = blockIdx.x;
  int b = blk >> 6, chunk = blk & 63;
  const float4* src = (const float4*)(inp + ((size_t)b * 5 + 1) * HW
                                          + (size_t)chunk * 4096);
  int t = threadIdx.x;
  float s = 0.0f;
#pragma unroll
  for (int k = 0; k < 4; ++k) {
    float4 v = src[t + k * 256];
    s += (v.x + v.y) + (v.z + v.w);
  }
  for (int off = 32; off; off >>= 1) s += __shfl_down(s, off);
  __shared__ float ws4[4];
  if ((t & 63) == 0) ws4[t >> 6] = s;
  __syncthreads();
  if (t == 0) partial[blk] = ws4[0] + ws4[1] + ws4[2] + ws4[3];
}

__global__ __launch_bounds__(256) void acquire_plain(
    const float* __restrict__ inp, const int* __restrict__ frames,
    const float* __restrict__ partial, float* __restrict__ out,
    uint32_t ku0, uint32_t ku1, uint32_t kn0, uint32_t kn1) {
  int b = blockIdx.x >> 10;
  int rem = ((blockIdx.x & 1023) << 8) | threadIdx.x;
  __shared__ float s_bias;
  if (threadIdx.x < 64) {
    float s = partial[(b << 6) | threadIdx.x];
    for (int off = 32; off; off >>= 1) s += __shfl_down(s, off);
    if (threadIdx.x == 0) s_bias = fmaxf(s * (1.0f / 262144.0f), 0.0f);
  }
  const float* pb = inp + (size_t)b * 5 * HW;
  float img = pb[rem];
  float fw  = fmaxf(pb[2 * HW + rem], 0.0f);
  float fa  = fmaxf(pb[3 * HW + rem], 0.0f);
  float gw  = fmaxf(pb[4 * HW + rem], 0.0f);
  __syncthreads();
  float base = img + s_bias;
  int nf = frames[b];
  float nfa = -fa;
  float fac = fa * 0.52876637294f;
  uint32_t idx = (uint32_t)(b * 16) * (uint32_t)HW + (uint32_t)rem;
  float acc = 0.0f;
  for (int f = 0; f < nf; ++f) {
    uint32_t ub = rbits32(ku0, ku1, idx);
    uint32_t nb = rbits32(kn0, kn1, idx);
    idx += (uint32_t)HW;
    float u = unit_from_bits(ub);
    u = fminf(fmaxf(u, 1e-6f), 0.999999f);
    float pw = EXP2F(fmaf(nfa, LOG2F(-LOG2F(u)), fac));
    float z = sqrt2_erfinv(fmaf(unit_from_bits(nb), 2.0f, -0.99999994f));
    float s = fmaf(gw, z, fmaf(fw, pw, base));
    acc += fminf(fmaxf(s, 0.0f), 1.0f);
  }
  out[(size_t)b * HW + rem] = acc * RCPF((float)nf);
  float cpw = EXP2F(nfa * LOG2F(fa + 1.0f));
  out[ACQ_N + (size_t)b * HW + rem] = fminf(fmaxf(fmaf(fw, cpw, base), 0.0f), 1.0f);
}

extern "C" void kernel_launch(void* const* d_in, const int* in_sizes, int n_in,
                              void* d_out, int out_size, void* d_ws, size_t ws_size,
                              hipStream_t stream) {
  const float* inp    = (const float*)d_in[0];
  const int*   frames = (const int*)d_in[1];
  float* out = (float*)d_out;

  // jax_threefry_partitionable=True: split(key(42)) foldlike:
  // ku = cipher((0,42),(0,0)), kn = cipher((0,42),(0,1))
  uint32_t ku0, ku1, kn0, kn1;
  tf2x32_host(0u, 42u, 0u, 0u, ku0, ku1);
  tf2x32_host(0u, 42u, 0u, 1u, kn0, kn1);

  const size_t need = 10240 + (size_t)8 * HW * 4;
  if (ws_size >= need) {
    float*    partial  = (float*)d_ws;                    // 512 f32
    uint32_t* blockcnt = (uint32_t*)((char*)d_ws + 2048); // 512*4 u32
    uint32_t* slotidx  = (uint32_t*)((char*)d_ws + 10240);// 8*HW u32
    // no memset needed: every word is overwritten every launch
    count_cls<<<dim3(512), dim3(256), 0, stream>>>(inp, blockcnt, partial);
    scatter_cls<<<dim3(512), dim3(256), 0, stream>>>(inp, blockcnt, slotidx);
    acquire_cls<<<dim3(8192), dim3(256), 0, stream>>>(inp, frames, partial,
                                                      slotidx, out,
                                                      ku0, ku1, kn0, kn1);
  } else {
    float* partial = (float*)d_ws;   // 512 floats
    bias_partial<<<dim3(512), dim3(256), 0, stream>>>(inp, partial);
    acquire_plain<<<dim3(8192), dim3(256), 0, stream>>>(inp, frames, partial, out,
                                                        ku0, ku1, kn0, kn1);
  }
}

// Round 9
// 177.331 us; speedup vs baseline: 3.0951x; 1.0033x over previous
//
#include <hip/hip_runtime.h>
#include <stdint.h>

#define HW 262144            // 512*512
#define ACQ_N 2097152        // 8*1*512*512

// hw-native transcendentals (1 instr each)
#define LOG2F(x) __builtin_amdgcn_logf(x)
#define EXP2F(x) __builtin_amdgcn_exp2f(x)
#define SQRTF(x) __builtin_amdgcn_sqrtf(x)
#define RCPF(x)  __builtin_amdgcn_rcpf(x)

#define ROTL(x, r) __builtin_amdgcn_alignbit((x), (x), (32 - (r)) & 31)

// ---------- host-side threefry2x32 for key derivation ----------
static inline void tf2x32_host(uint32_t k0, uint32_t k1, uint32_t c0, uint32_t c1,
                               uint32_t& o0, uint32_t& o1) {
  const uint32_t ks2 = k0 ^ k1 ^ 0x1BD11BDAu;
  uint32_t x0 = c0 + k0, x1 = c1 + k1;
#define TFR(r) { x0 += x1; x1 = (x1 << (r)) | (x1 >> (32 - (r))); x1 ^= x0; }
  TFR(13) TFR(15) TFR(26) TFR(6)
  x0 += k1;  x1 += ks2 + 1u;
  TFR(17) TFR(29) TFR(16) TFR(24)
  x0 += ks2; x1 += k0 + 2u;
  TFR(13) TFR(15) TFR(26) TFR(6)
  x0 += k0;  x1 += k1 + 3u;
  TFR(17) TFR(29) TFR(16) TFR(24)
  x0 += k1;  x1 += ks2 + 4u;
  TFR(13) TFR(15) TFR(26) TFR(6)
  x0 += ks2; x1 += k0 + 5u;
#undef TFR
  o0 = x0; o1 = x1;
}

// device: partitionable random_bits(32) for counter (0, idx): o0^o1
__device__ __forceinline__ uint32_t rbits32(uint32_t k0, uint32_t k1, uint32_t idx) {
  const uint32_t ks2 = k0 ^ k1 ^ 0x1BD11BDAu;
  uint32_t x0 = k0, x1 = idx + k1;
#define TFR(r) { x0 += x1; x1 = ROTL(x1, r); x1 ^= x0; }
  TFR(13) TFR(15) TFR(26) TFR(6)
  x0 += k1;  x1 += ks2 + 1u;
  TFR(17) TFR(29) TFR(16) TFR(24)
  x0 += ks2; x1 += k0 + 2u;
  TFR(13) TFR(15) TFR(26) TFR(6)
  x0 += k0;  x1 += k1 + 3u;
  TFR(17) TFR(29) TFR(16) TFR(24)
  x0 += k1;  x1 += ks2 + 4u;
  TFR(13) TFR(15) TFR(26) TFR(6)
  x0 += ks2; x1 += k0 + 5u;
#undef TFR
  return x0 ^ x1;
}

__device__ __forceinline__ float unit_from_bits(uint32_t b) {
  return __uint_as_float((b >> 9) | 0x3F800000u) - 1.0f;
}

// z = sqrt(2)*erfinv(x), Giles poly pre-scaled by sqrt(2); far branch real-branched.
__device__ __forceinline__ float sqrt2_erfinv(float x) {
  float ome = fmaf(-x, x, 1.0f);
  float w = -0.69314718056f * LOG2F(ome);
  float wn = w - 2.5f;
  float p = 3.974065e-08f;
  p = fmaf(p, wn, 4.854641e-07f);
  p = fmaf(p, wn, -4.982823e-06f);
  p = fmaf(p, wn, -6.210531e-06f);
  p = fmaf(p, wn, 3.091200e-04f);
  p = fmaf(p, wn, -1.773035e-03f);
  p = fmaf(p, wn, -5.908135e-03f);
  p = fmaf(p, wn, 3.488029e-01f);
  p = fmaf(p, wn, 2.123314e+00f);
  if (__builtin_expect(w >= 5.0f, 0)) {
    float wf = SQRTF(w) - 3.0f;
    float q = -2.831458e-04f;
    q = fmaf(q, wf, 1.427657e-04f);
    q = fmaf(q, wf, 1.908260e-03f);
    q = fmaf(q, wf, -5.195013e-03f);
    q = fmaf(q, wf, 8.116892e-03f);
    q = fmaf(q, wf, -1.0779791e-02f);
    q = fmaf(q, wf, 1.3348579e-02f);
    q = fmaf(q, wf, 1.416582e+00f);
    q = fmaf(q, wf, 4.006434e+00f);
    p = q;
  }
  return p * x;
}

// ---------- bias partial sums: relu(mean(inp[:,1])) stage 1 ----------
__global__ __launch_bounds__(256) void bias_partial(const float* __restrict__ inp,
                                                    float* __restrict__ partial) {
  int blk = blockIdx.x;                 // 512 blocks: 8 batches x 64 chunks
  int b = blk >> 6, chunk = blk & 63;
  const float4* src = (const float4*)(inp + ((size_t)b * 5 + 1) * HW
                                          + (size_t)chunk * 4096);
  int t = threadIdx.x;
  float s = 0.0f;
#pragma unroll
  for (int k = 0; k < 4; ++k) {
    float4 v = src[t + k * 256];
    s += (v.x + v.y) + (v.z + v.w);
  }
  for (int off = 32; off; off >>= 1) s += __shfl_down(s, off);
  __shared__ float ws4[4];
  if ((t & 63) == 0) ws4[t >> 6] = s;
  __syncthreads();
  if (t == 0) partial[blk] = ws4[0] + ws4[1] + ws4[2] + ws4[3];
}

// ---------- fused local-sort main kernel ----------
// 2048 blocks x 256 threads; each block owns 1024 consecutive pixels of one
// batch. Stable in-LDS partition by class (fw>0, gw>0) -> 16 slot-groups of 64;
// class-pure groups skip unneeded cipher halves. All global R/W coalesced.
__global__ __launch_bounds__(256) void acquire_local(
    const float* __restrict__ inp, const int* __restrict__ frames,
    const float* __restrict__ partial, float* __restrict__ out,
    uint32_t ku0, uint32_t ku1, uint32_t kn0, uint32_t kn1) {
  __shared__ float s_img[1024], s_fw[1024], s_fa[1024], s_gw[1024], s_res[1024];
  __shared__ unsigned short s_ord[1024];
  __shared__ unsigned char s_cls[1024];
  __shared__ uint32_t gcnt[16][4], gbase[16][4];
  __shared__ float s_bias;

  int tid = threadIdx.x, wid = tid >> 6, lane = tid & 63;
  int b = blockIdx.x >> 8;                    // 256 blocks per batch
  int pxbase = (blockIdx.x & 255) << 10;      // batch-local pixel base

  // bias finalize (wave 0) from the 64 per-chunk partials
  if (tid < 64) {
    float s = partial[(b << 6) | tid];
    for (int off = 32; off; off >>= 1) s += __shfl_down(s, off);
    if (tid == 0) s_bias = fmaxf(s * (1.0f / 262144.0f), 0.0f);
  }
  __syncthreads();
  float bias = s_bias;

  const float* pb = inp + (size_t)b * 5 * HW + pxbase;
  float* outa = out + (size_t)b * HW + pxbase;
  float* outc = out + ACQ_N + (size_t)b * HW + pxbase;
  uint64_t below = (1ull << lane) - 1ull;

  // stage + classify + center write (all coalesced)
#pragma unroll
  for (int k = 0; k < 4; ++k) {
    int i = (k << 8) + tid;
    float img = pb[i];
    float fw  = fmaxf(pb[2 * HW + i], 0.0f);
    float fa  = fmaxf(pb[3 * HW + i], 0.0f);
    float gw  = fmaxf(pb[4 * HW + i], 0.0f);
    s_img[i] = img; s_fw[i] = fw; s_fa[i] = fa; s_gw[i] = gw;
    int cls = (fw > 0.0f ? 1 : 0) | (gw > 0.0f ? 2 : 0);
    s_cls[i] = (unsigned char)cls;
    uint64_t ball[4];
#pragma unroll
    for (int c = 0; c < 4; ++c) ball[c] = __ballot(cls == c);
    if (lane == 0) {
#pragma unroll
      for (int c = 0; c < 4; ++c)
        gcnt[(k << 2) | wid][c] = (uint32_t)__popcll(ball[c]);
    }
    // center = clip(base + fw*(1/(fa+1))^fa, 0, 1)
    float base = img + bias;
    float cpw = EXP2F(-fa * LOG2F(fa + 1.0f));
    outc[i] = fminf(fmaxf(fmaf(fw, cpw, base), 0.0f), 1.0f);
  }
  __syncthreads();

  // exclusive prefix: gbase[g][c] = sum_{c'<c} tot[c'] + sum_{g'<g} gcnt[g'][c]
  if (tid < 64) {
    int g = tid >> 2, c = tid & 3;
    uint32_t pre = 0;
    for (int gg = 0; gg < g; ++gg) pre += gcnt[gg][c];
    uint32_t cbase = 0;
    for (int cc = 0; cc < c; ++cc) {
      uint32_t t = 0;
      for (int gg = 0; gg < 16; ++gg) t += gcnt[gg][cc];
      cbase += t;
    }
    gbase[g][c] = cbase + pre;
  }
  __syncthreads();

  // scatter local order (stable partition by class)
#pragma unroll
  for (int k = 0; k < 4; ++k) {
    int i = (k << 8) + tid;
    int cls = s_cls[i];
    uint64_t ball[4];
#pragma unroll
    for (int c = 0; c < 4; ++c) ball[c] = __ballot(cls == c);
    int rank = __popcll(ball[cls] & below);
    s_ord[gbase[(k << 2) | wid][cls] + rank] = (unsigned short)i;
  }
  __syncthreads();

  // process: 64-slot groups are (mostly) class-pure
  int nf = frames[b];                          // block-uniform
  uint32_t idx0 = ((uint32_t)b << 22) + (uint32_t)(pxbase);
#pragma unroll
  for (int j = 0; j < 4; ++j) {
    int s = (j << 8) + tid;
    int i = s_ord[s];
    float img = s_img[i], fw = s_fw[i], fa = s_fa[i], gw = s_gw[i];
    float base = img + bias;
    bool fAny = __any(fw > 0.0f);              // wave-group-uniform
    bool gAny = __any(gw > 0.0f);
    float res;
    if (fAny || gAny) {
      float nfa = -fa;
      float fac = fa * 0.52876637294f;         // fa*log2(ln2)
      uint32_t idx = idx0 + (uint32_t)i;
      float acc = 0.0f;
      for (int f = 0; f < nf; ++f) {
        float term = base;
        if (fAny) {
          uint32_t ub = rbits32(ku0, ku1, idx);
          float u = unit_from_bits(ub);
          u = fminf(fmaxf(u, 1e-6f), 0.999999f);
          float pw = EXP2F(fmaf(nfa, LOG2F(-LOG2F(u)), fac));
          term = fmaf(fw, pw, term);
        }
        if (gAny) {
          uint32_t nb = rbits32(kn0, kn1, idx);
          float z = sqrt2_erfinv(fmaf(unit_from_bits(nb), 2.0f, -0.99999994f));
          term = fmaf(gw, z, term);
        }
        idx += (uint32_t)HW;
        acc += fminf(fmaxf(term, 0.0f), 1.0f);
      }
      res = acc * RCPF((float)nf);
    } else {
      res = fminf(fmaxf(base, 0.0f), 1.0f);    // all frames identical
    }
    s_res[i] = res;
  }
  __syncthreads();

  // coalesced write-back
#pragma unroll
  for (int k = 0; k < 4; ++k) {
    int i = (k << 8) + tid;
    outa[i] = s_res[i];
  }
}

extern "C" void kernel_launch(void* const* d_in, const int* in_sizes, int n_in,
                              void* d_out, int out_size, void* d_ws, size_t ws_size,
                              hipStream_t stream) {
  const float* inp    = (const float*)d_in[0];
  const int*   frames = (const int*)d_in[1];
  float* out = (float*)d_out;
  float* partial = (float*)d_ws;   // 512 floats

  // jax_threefry_partitionable=True: split(key(42)) foldlike:
  // ku = cipher((0,42),(0,0)), kn = cipher((0,42),(0,1))
  uint32_t ku0, ku1, kn0, kn1;
  tf2x32_host(0u, 42u, 0u, 0u, ku0, ku1);
  tf2x32_host(0u, 42u, 0u, 1u, kn0, kn1);

  bias_partial<<<dim3(512), dim3(256), 0, stream>>>(inp, partial);
  acquire_local<<<dim3(2048), dim3(256), 0, stream>>>(inp, frames, partial, out,
                                                      ku0, ku1, kn0, kn1);
}